// Round 1
// baseline (870.685 us; speedup 1.0000x reference)
//
#include <hip/hip_runtime.h>
#include <math.h>

#define N_NODES 100000
#define C_CH    64
#define E_EDGES 1200000
#define KD      32
#define HID     256

// ---------------------------------------------------------------------------
// K1: depthwise conv message passing.
// One wave (64 lanes) per edge; lane = channel c.
// kernel[e][c] = sum_k kernel_basis[e][k] * kernel_W[c][k]
// x1[dst] += x[src] * kernel[e]
// Per-lane weight column kernel_W[c][0:32] hoisted to registers (once per
// thread). kernel_basis row shared across lanes via __shfl broadcast.
// ---------------------------------------------------------------------------
__global__ __launch_bounds__(256) void edge_kernel(
    const float* __restrict__ x,
    const float* __restrict__ kb,
    const int*   __restrict__ ei,
    const float* __restrict__ kW,
    float*       __restrict__ x1)
{
    const int lane = threadIdx.x & 63;
    const int wave = threadIdx.x >> 6;
    const int waves_total = gridDim.x * 4;
    const int wid = blockIdx.x * 4 + wave;

    // weight column for this lane's channel
    float wcol[KD];
    #pragma unroll
    for (int k = 0; k < KD; ++k) wcol[k] = kW[lane * KD + k];

    for (int e = wid; e < E_EDGES; e += waves_total) {
        int src = ei[e];
        int dst = ei[E_EDGES + e];
        // lane k (k<32) holds kernel_basis[e][k]
        float bv = (lane < KD) ? kb[(size_t)e * KD + lane] : 0.f;
        float acc = 0.f;
        #pragma unroll
        for (int k = 0; k < KD; ++k) {
            acc += __shfl(bv, k, 64) * wcol[k];
        }
        if ((unsigned)src < (unsigned)N_NODES && (unsigned)dst < (unsigned)N_NODES) {
            float xv = x[(size_t)src * C_CH + lane];
            atomicAdd(&x1[(size_t)dst * C_CH + lane], xv * acc);
        }
    }
}

// ---------------------------------------------------------------------------
// K2: fused conv_bias + LayerNorm + MLP(64->256->64, exact GELU) + layerscale
// + residual. 256 threads; each iteration handles 4 nodes (one per wave for
// the LN phase). W1 row / W2 chunk cached in registers per thread.
// ---------------------------------------------------------------------------
__global__ __launch_bounds__(256, 2) void node_kernel(
    const float* __restrict__ x,
    const float* __restrict__ x1,
    const float* __restrict__ conv_bias,
    const float* __restrict__ gamma,
    const float* __restrict__ beta,
    const float* __restrict__ W1,
    const float* __restrict__ b1,
    const float* __restrict__ W2,
    const float* __restrict__ b2,
    const float* __restrict__ ls,
    float*       __restrict__ out)
{
    __shared__ float lnbuf[4][C_CH];   // LN output, [node_in_group][c]
    __shared__ float gbuf[4][HID];     // GELU output, [node_in_group][j]
    __shared__ float red[3][4][C_CH];  // h2 partials from waves 1..3

    const int t    = threadIdx.x;
    const int lane = t & 63;           // channel for LN / output channel for h2
    const int w    = t >> 6;           // wave id == partial id p

    // ---- per-thread weight registers (loaded once per block lifetime) ----
    float w1r[C_CH];                   // W1[t][0:64]  (h1[j=t])
    #pragma unroll
    for (int i = 0; i < C_CH; ++i) w1r[i] = W1[t * C_CH + i];
    float w2r[C_CH];                   // W2[lane][w*64 : w*64+64]
    #pragma unroll
    for (int i = 0; i < C_CH; ++i) w2r[i] = W2[lane * HID + w * 64 + i];
    const float b1r    = b1[t];
    const float biasc  = conv_bias[lane];
    const float gammac = gamma[lane];
    const float betac  = beta[lane];
    const float b2c    = b2[lane];
    const float lsc    = ls[lane];

    const int ngroups = N_NODES / 4;   // 25000, exact
    for (int g = blockIdx.x; g < ngroups; g += gridDim.x) {
        const int node = g * 4 + w;

        // ---- phase 1: bias + LayerNorm (wave w handles node g*4+w) ----
        float v = x1[(size_t)node * C_CH + lane] + biasc;
        float s = v, ss = v * v;
        #pragma unroll
        for (int off = 32; off > 0; off >>= 1) {
            s  += __shfl_xor(s,  off, 64);
            ss += __shfl_xor(ss, off, 64);
        }
        float mu   = s * (1.f / 64.f);
        float var  = ss * (1.f / 64.f) - mu * mu;
        float rstd = rsqrtf(var + 1e-5f);
        lnbuf[w][lane] = (v - mu) * rstd * gammac + betac;
        __syncthreads();

        // ---- phase 2: h1[j=t] + exact GELU, for all 4 nodes ----
        #pragma unroll
        for (int nn = 0; nn < 4; ++nn) {
            float acc = b1r;
            #pragma unroll
            for (int i = 0; i < C_CH; ++i) acc += lnbuf[nn][i] * w1r[i];
            gbuf[nn][t] = 0.5f * acc * (1.f + erff(acc * 0.70710678118654752f));
        }
        __syncthreads();

        // ---- phase 3: h2 partial (wave w covers j in [w*64, w*64+64)) ----
        float part[4];
        #pragma unroll
        for (int nn = 0; nn < 4; ++nn) {
            float acc = 0.f;
            #pragma unroll
            for (int i = 0; i < C_CH; ++i) acc += gbuf[nn][w * 64 + i] * w2r[i];
            part[nn] = acc;
        }
        if (w > 0) {
            #pragma unroll
            for (int nn = 0; nn < 4; ++nn) red[w - 1][nn][lane] = part[nn];
        }
        __syncthreads();

        // ---- phase 4: reduce + bias + layerscale + residual (wave 0) ----
        if (w == 0) {
            #pragma unroll
            for (int nn = 0; nn < 4; ++nn) {
                const int nd = g * 4 + nn;
                float h2 = part[nn] + red[0][nn][lane] + red[1][nn][lane]
                         + red[2][nn][lane] + b2c;
                out[(size_t)nd * C_CH + lane] =
                    lsc * h2 + x[(size_t)nd * C_CH + lane];
            }
        }
        __syncthreads();   // protect red/lnbuf/gbuf for next iteration
    }
}

extern "C" void kernel_launch(void* const* d_in, const int* in_sizes, int n_in,
                              void* d_out, int out_size, void* d_ws, size_t ws_size,
                              hipStream_t stream) {
    const float* x   = (const float*)d_in[0];
    const float* kb  = (const float*)d_in[1];
    // d_in[2] = fiber_kernel_basis (unused)
    const int*   ei  = (const int*)d_in[3];
    const float* kW  = (const float*)d_in[4];
    const float* cb  = (const float*)d_in[5];
    const float* gm  = (const float*)d_in[6];
    const float* bt  = (const float*)d_in[7];
    const float* W1  = (const float*)d_in[8];
    const float* b1  = (const float*)d_in[9];
    const float* W2  = (const float*)d_in[10];
    const float* b2  = (const float*)d_in[11];
    const float* ls  = (const float*)d_in[12];
    float* out = (float*)d_out;

    float* x1 = (float*)d_ws;          // [N, C] scatter accumulator
    hipMemsetAsync(x1, 0, (size_t)N_NODES * C_CH * sizeof(float), stream);

    edge_kernel<<<4096, 256, 0, stream>>>(x, kb, ei, kW, x1);
    node_kernel<<<1024, 256, 0, stream>>>(x, x1, cb, gm, bt, W1, b1, W2, b2, ls, out);
}

// Round 2
// 858.997 us; speedup vs baseline: 1.0136x; 1.0136x over previous
//
#include <hip/hip_runtime.h>
#include <math.h>

#define N_NODES 100000
#define C_CH    64
#define E_EDGES 1200000
#define KD      32
#define HID     256
#define NPG     16      // nodes per group in node_kernel

// ---------------------------------------------------------------------------
// K1: depthwise conv message passing. One wave per edge; lane = channel.
// e is forced wave-uniform (readfirstlane) so ei / kernel_basis row loads
// become scalar (s_load) ops; the 32-term dot is FMA with SGPR operands —
// no shuffles, no LDS. Scatter uses HW fp32 atomics (unsafeAtomicAdd).
// ---------------------------------------------------------------------------
__global__ __launch_bounds__(256) void edge_kernel(
    const float* __restrict__ x,
    const float* __restrict__ kb,
    const int*   __restrict__ ei,
    const float* __restrict__ kW,
    float*       __restrict__ x1)
{
    const int lane = threadIdx.x & 63;
    const int wave = threadIdx.x >> 6;
    const int waves_total = gridDim.x * 4;
    const int wid = blockIdx.x * 4 + wave;

    // weight column for this lane's channel
    float wcol[KD];
    #pragma unroll
    for (int k = 0; k < KD; ++k) wcol[k] = kW[lane * KD + k];

    for (int e = wid; e < E_EDGES; e += waves_total) {
        const int eu  = __builtin_amdgcn_readfirstlane(e);   // wave-uniform
        const int src = ei[eu];
        const int dst = ei[E_EDGES + eu];
        const float* __restrict__ kbrow = kb + (size_t)eu * KD;

        float acc = 0.f;
        #pragma unroll
        for (int k = 0; k < KD; ++k) acc += kbrow[k] * wcol[k];

        if ((unsigned)src < (unsigned)N_NODES && (unsigned)dst < (unsigned)N_NODES) {
            float xv = x[(size_t)src * C_CH + lane];
            unsafeAtomicAdd(&x1[(size_t)dst * C_CH + lane], xv * acc);
        }
    }
}

// ---------------------------------------------------------------------------
// K2: fused conv_bias + LayerNorm + MLP(64->256->64, exact GELU) + layerscale
// + residual. 256 threads; 16 nodes per barrier cycle. W1 row / W2 chunk in
// registers per thread; activations through LDS with float4 reads.
// ---------------------------------------------------------------------------
__global__ __launch_bounds__(256, 2) void node_kernel(
    const float* __restrict__ x,
    const float* __restrict__ x1,
    const float* __restrict__ conv_bias,
    const float* __restrict__ gamma,
    const float* __restrict__ beta,
    const float* __restrict__ W1,
    const float* __restrict__ b1,
    const float* __restrict__ W2,
    const float* __restrict__ b2,
    const float* __restrict__ ls,
    float*       __restrict__ out)
{
    __shared__ float lnbuf[NPG][C_CH];        // LN output      (4 KB)
    __shared__ float gbuf[NPG][HID];          // GELU output   (16 KB)
    __shared__ float red[4][NPG][C_CH];       // h2 partials   (16 KB)

    const int t    = threadIdx.x;
    const int lane = t & 63;
    const int w    = t >> 6;

    // ---- per-thread weight registers ----
    float w1r[C_CH];                          // W1[t][0:64]
    #pragma unroll
    for (int i = 0; i < C_CH; ++i) w1r[i] = W1[t * C_CH + i];
    float w2r[C_CH];                          // W2[lane][w*64 : w*64+64]
    #pragma unroll
    for (int i = 0; i < C_CH; ++i) w2r[i] = W2[lane * HID + w * 64 + i];
    const float b1r    = b1[t];
    const float biasc  = conv_bias[lane];
    const float gammac = gamma[lane];
    const float betac  = beta[lane];
    const float b2c    = b2[lane];
    const float lsc    = ls[lane];

    const int ngroups = N_NODES / NPG;        // 6250, exact
    for (int g = blockIdx.x; g < ngroups; g += gridDim.x) {
        const int base = g * NPG;

        // ---- phase 1: bias + LN; wave w handles local nodes 4w..4w+3 ----
        #pragma unroll
        for (int q = 0; q < 4; ++q) {
            const int ln_local = w * 4 + q;
            float v = x1[(size_t)(base + ln_local) * C_CH + lane] + biasc;
            float s = v, ss = v * v;
            #pragma unroll
            for (int off = 32; off > 0; off >>= 1) {
                s  += __shfl_xor(s,  off, 64);
                ss += __shfl_xor(ss, off, 64);
            }
            float mu   = s * (1.f / 64.f);
            float var  = ss * (1.f / 64.f) - mu * mu;
            float rstd = rsqrtf(var + 1e-5f);
            lnbuf[ln_local][lane] = (v - mu) * rstd * gammac + betac;
        }
        __syncthreads();

        // ---- phase 2: h1[j=t] + exact GELU, 16 nodes ----
        #pragma unroll
        for (int nn = 0; nn < NPG; ++nn) {
            const float4* __restrict__ lp = (const float4*)lnbuf[nn];
            float acc = b1r;
            #pragma unroll
            for (int i4 = 0; i4 < C_CH / 4; ++i4) {
                float4 l = lp[i4];
                acc += l.x * w1r[i4*4+0] + l.y * w1r[i4*4+1]
                     + l.z * w1r[i4*4+2] + l.w * w1r[i4*4+3];
            }
            gbuf[nn][t] = 0.5f * acc * (1.f + erff(acc * 0.70710678f));
        }
        __syncthreads();

        // ---- phase 3: h2 partials; wave w covers j in [w*64, w*64+64) ----
        #pragma unroll
        for (int nn = 0; nn < NPG; ++nn) {
            const float4* __restrict__ gp = (const float4*)&gbuf[nn][w * 64];
            float acc = 0.f;
            #pragma unroll
            for (int i4 = 0; i4 < C_CH / 4; ++i4) {
                float4 gv = gp[i4];
                acc += gv.x * w2r[i4*4+0] + gv.y * w2r[i4*4+1]
                     + gv.z * w2r[i4*4+2] + gv.w * w2r[i4*4+3];
            }
            red[w][nn][lane] = acc;
        }
        __syncthreads();

        // ---- phase 4: all waves reduce; wave w -> nodes 4w..4w+3 ----
        #pragma unroll
        for (int q = 0; q < 4; ++q) {
            const int nn = w * 4 + q;
            const int nd = base + nn;
            float h2 = red[0][nn][lane] + red[1][nn][lane]
                     + red[2][nn][lane] + red[3][nn][lane] + b2c;
            out[(size_t)nd * C_CH + lane] =
                lsc * h2 + x[(size_t)nd * C_CH + lane];
        }
        __syncthreads();   // protect LDS for next group
    }
}

extern "C" void kernel_launch(void* const* d_in, const int* in_sizes, int n_in,
                              void* d_out, int out_size, void* d_ws, size_t ws_size,
                              hipStream_t stream) {
    const float* x   = (const float*)d_in[0];
    const float* kb  = (const float*)d_in[1];
    // d_in[2] = fiber_kernel_basis (unused)
    const int*   ei  = (const int*)d_in[3];
    const float* kW  = (const float*)d_in[4];
    const float* cb  = (const float*)d_in[5];
    const float* gm  = (const float*)d_in[6];
    const float* bt  = (const float*)d_in[7];
    const float* W1  = (const float*)d_in[8];
    const float* b1  = (const float*)d_in[9];
    const float* W2  = (const float*)d_in[10];
    const float* b2  = (const float*)d_in[11];
    const float* ls  = (const float*)d_in[12];
    float* out = (float*)d_out;

    float* x1 = (float*)d_ws;          // [N, C] scatter accumulator
    hipMemsetAsync(x1, 0, (size_t)N_NODES * C_CH * sizeof(float), stream);

    edge_kernel<<<4096, 256, 0, stream>>>(x, kb, ei, kW, x1);
    node_kernel<<<1024, 256, 0, stream>>>(x, x1, cb, gm, bt, W1, b1, W2, b2, ls, out);
}